// Round 1
// baseline (462.152 us; speedup 1.0000x reference)
//
#include <hip/hip_runtime.h>
#include <hip/hip_bf16.h>

typedef int   i32x4 __attribute__((ext_vector_type(4)));
typedef float f32x4 __attribute__((ext_vector_type(4)));

constexpr int K_IC = 4096;   // inner dim
constexpr int N_OC = 4096;   // output channels
constexpr int GROUPS = 32;   // quant groups (group size 128)

// ---------------------------------------------------------------------------
// Fused prep (UNCHANGED this round): blocks [0, M) token quant -> int8;
// blocks [M, M+N_OC) weight prep -> w8 = qw - zero + sT[g][oc] scales.
// ---------------------------------------------------------------------------
__global__ __launch_bounds__(256) void prep_kernel(const float* __restrict__ x,
                                                   const int* __restrict__ qweight,
                                                   const int* __restrict__ zeros,
                                                   const int* __restrict__ qstep,
                                                   const float* __restrict__ base_scales,
                                                   const float* __restrict__ step_scales,
                                                   char* __restrict__ qx8,
                                                   char* __restrict__ w8,
                                                   float* __restrict__ sT,
                                                   float* __restrict__ x_scales,
                                                   int M) {
    const int tid = threadIdx.x;
    if ((int)blockIdx.x < M) {
        // ---- token-wise int8 quant ----
        const int m = blockIdx.x;
        const float4* xr = (const float4*)(x + (size_t)m * K_IC);
        float4 v[4];
        float amax = 0.f;
#pragma unroll
        for (int i = 0; i < 4; ++i) {
            v[i] = xr[i * 256 + tid];
            amax = fmaxf(amax, fmaxf(fmaxf(fabsf(v[i].x), fabsf(v[i].y)),
                                     fmaxf(fabsf(v[i].z), fabsf(v[i].w))));
        }
#pragma unroll
        for (int off = 32; off > 0; off >>= 1)
            amax = fmaxf(amax, __shfl_xor(amax, off, 64));
        __shared__ float wmax[4];
        if ((tid & 63) == 0) wmax[tid >> 6] = amax;
        __syncthreads();
        amax = fmaxf(fmaxf(wmax[0], wmax[1]), fmaxf(wmax[2], wmax[3]));

        const float scale = amax / 127.0f;       // reference x_scales (un-clamped)
        if (tid == 0) x_scales[m] = scale;
        const float inv = 1.0f / fmaxf(scale, 1e-8f);

        char4* qr = (char4*)(qx8 + (size_t)m * K_IC);
#pragma unroll
        for (int i = 0; i < 4; ++i) {
            char4 o;
            o.x = (char)(int)fminf(fmaxf(rintf(v[i].x * inv), -127.f), 127.f);
            o.y = (char)(int)fminf(fmaxf(rintf(v[i].y * inv), -127.f), 127.f);
            o.z = (char)(int)fminf(fmaxf(rintf(v[i].z * inv), -127.f), 127.f);
            o.w = (char)(int)fminf(fmaxf(rintf(v[i].w * inv), -127.f), 127.f);
            qr[i * 256 + tid] = o;
        }
    } else {
        // ---- weight prep: w8 = qw - zero;  sT[g][oc] = base + step*qstep ----
        const int oc = blockIdx.x - M;
        const int4* qwr = (const int4*)(qweight + (size_t)oc * K_IC);
        char4* wr = (char4*)(w8 + (size_t)oc * K_IC);
#pragma unroll
        for (int i = 0; i < 4; ++i) {
            const int idx = i * 256 + tid;          // int4 index within the row
            const int g = idx >> 5;                 // 32 int4 per group of 128
            const int zp = zeros[oc * GROUPS + g];
            int4 a = qwr[idx];
            char4 o;
            o.x = (char)(a.x - zp); o.y = (char)(a.y - zp);
            o.z = (char)(a.z - zp); o.w = (char)(a.w - zp);
            wr[idx] = o;
        }
        if (tid < GROUPS) {
            sT[(size_t)tid * N_OC + oc] =
                base_scales[oc] + step_scales[oc] * (float)qstep[oc * GROUPS + tid];
        }
    }
}

// ---------------------------------------------------------------------------
// int8 MFMA GEMM, 256x256 tile, BK=128 (= group size), 8 waves (2M x 4N),
// per-wave 128x64. Double-buffered LDS (128 KiB) with prefetch issued right
// after the single per-tile barrier: the barrier's vmcnt(0) drain then waits
// on loads issued one full K-tile (~2300 MFMA cycles) earlier -> HBM latency
// hidden (T3-minimum schedule). XOR chunk swizzle (verified: 0 bank conflicts)
// via linear LDS dest + pre-swizzled global source (global_load_lds rule).
// Per group: accF[i][j] += sT[g][col_j] * (float)P[i][j]; P exact (<2^18).
// ---------------------------------------------------------------------------
#define BM 256
#define BN 256
#define BK 128

__device__ inline void async16(const char* g, char* l) {
    __builtin_amdgcn_global_load_lds(
        (const __attribute__((address_space(1))) void*)g,
        (__attribute__((address_space(3))) void*)l,
        16, 0, 0);
}

__global__ __launch_bounds__(512, 2) void gemm_kernel(const char* __restrict__ A8,
                                                      const char* __restrict__ B8,
                                                      const float* __restrict__ sT,
                                                      const float* __restrict__ x_scales,
                                                      float* __restrict__ out) {
    __shared__ __attribute__((aligned(16))) char As[2][BM][BK];   // 64 KiB
    __shared__ __attribute__((aligned(16))) char Bs[2][BN][BK];   // 64 KiB

    const int tid  = threadIdx.x;
    const int lane = tid & 63;
    const int wave = tid >> 6;       // 0..7
    const int waveM = wave >> 2;     // 0..1 -> 128 rows each
    const int waveN = wave & 3;      // 0..3 -> 64 cols each

    // T1: XCD-aware swizzle of the flat 512-block grid (nwg % 8 == 0)
    const int GX   = N_OC / BN;                       // 16
    const int flat = blockIdx.y * GX + blockIdx.x;
    const int nwg  = GX * gridDim.y;
    int swz = flat;
    if ((nwg & 7) == 0) swz = (flat & 7) * (nwg >> 3) + (flat >> 3);
    const int bn = swz & (GX - 1);
    const int bm = swz / GX;

    f32x4 accF[8][4] = {};
    const i32x4 zeroq = {0, 0, 0, 0};   // persistent MFMA C-init (D != C)

    // staging: LDS dest = wave-uniform base + lane*16 (linear); the global
    // SOURCE chunk is pre-swizzled: physical chunk p at row r holds logical
    // chunk p ^ (r & 7)  (involution; same XOR applied on the read side)
    const int rowInB = tid >> 3;                                   // 0..63
    const int chunk  = tid & 7;
    const int srcOff = ((chunk ^ (rowInB & 7)) * 16);              // bytes
    const char* Ap = A8 + (size_t)(bm * BM + rowInB) * K_IC + srcOff;
    const char* Bp = B8 + (size_t)(bn * BN + rowInB) * K_IC + srcOff;

    auto STAGE = [&](int b, int t) {
        const int k0 = t * BK;
#pragma unroll
        for (int i = 0; i < 4; ++i)
            async16(Ap + (size_t)(i * 64) * K_IC + k0, &As[b][rowInB + i * 64][chunk * 16]);
#pragma unroll
        for (int i = 0; i < 4; ++i)
            async16(Bp + (size_t)(i * 64) * K_IC + k0, &Bs[b][rowInB + i * 64][chunk * 16]);
    };

    const int mrow = waveM * 128 + (lane & 15);
    const int nrow = waveN * 64 + (lane & 15);
    const int q    = lane >> 4;          // K-quad (16 B each)
    const int sw   = lane & 7;           // row&7 of every fragment row this lane reads
    const int colBase = bn * BN + waveN * 64 + (lane & 15);

    // per-group column scales, software-pipelined one tile ahead
    float scolC[4], scolN[4];
    {
        const float* sg = sT + colBase;
#pragma unroll
        for (int j = 0; j < 4; ++j) scolN[j] = sg[j * 16];
    }

    STAGE(0, 0);

    for (int t = 0; t < GROUPS; ++t) {   // one group == one K-tile (128)
        const int c = t & 1;
        // barrier drain waits on tile t's loads (issued one full tile ago)
        __syncthreads();
        if (t + 1 < GROUPS) STAGE(c ^ 1, t + 1);

#pragma unroll
        for (int j = 0; j < 4; ++j) scolC[j] = scolN[j];
        if (t + 1 < GROUPS) {
            const float* sg = sT + (size_t)(t + 1) * N_OC + colBase;
#pragma unroll
            for (int j = 0; j < 4; ++j) scolN[j] = sg[j * 16];
        }

        // B fragments: held for the whole tile (8 x ds_read_b128, 32 VGPR)
        i32x4 bq[4][2];
#pragma unroll
        for (int j = 0; j < 4; ++j)
#pragma unroll
            for (int kk = 0; kk < 2; ++kk)
                bq[j][kk] = *(const i32x4*)&Bs[c][nrow + j * 16][((kk * 4 + q) ^ sw) * 16];

        // 4 phases over m-pairs: A reads minimal (16 x b128/tile), 16 MFMA/phase
#pragma unroll
        for (int ph = 0; ph < 4; ++ph) {
            const int m0 = mrow + (2 * ph) * 16;
            const int m1 = mrow + (2 * ph + 1) * 16;
            i32x4 a0k0 = *(const i32x4*)&As[c][m0][((0 + q) ^ sw) * 16];
            i32x4 a0k1 = *(const i32x4*)&As[c][m0][((4 + q) ^ sw) * 16];
            i32x4 a1k0 = *(const i32x4*)&As[c][m1][((0 + q) ^ sw) * 16];
            i32x4 a1k1 = *(const i32x4*)&As[c][m1][((4 + q) ^ sw) * 16];
            __builtin_amdgcn_s_setprio(1);
#pragma unroll
            for (int j = 0; j < 4; ++j) {
                i32x4 p = __builtin_amdgcn_mfma_i32_16x16x64_i8(a0k0, bq[j][0], zeroq, 0, 0, 0);
                p = __builtin_amdgcn_mfma_i32_16x16x64_i8(a0k1, bq[j][1], p, 0, 0, 0);
#pragma unroll
                for (int r = 0; r < 4; ++r)
                    accF[2 * ph][j][r] += scolC[j] * (float)p[r];
                i32x4 p2 = __builtin_amdgcn_mfma_i32_16x16x64_i8(a1k0, bq[j][0], zeroq, 0, 0, 0);
                p2 = __builtin_amdgcn_mfma_i32_16x16x64_i8(a1k1, bq[j][1], p2, 0, 0, 0);
#pragma unroll
                for (int r = 0; r < 4; ++r)
                    accF[2 * ph + 1][j][r] += scolC[j] * (float)p2[r];
            }
            __builtin_amdgcn_s_setprio(0);
        }
    }

    // epilogue: C/D layout col=lane&15, row=(lane>>4)*4+reg (dtype-independent)
    const int colT = lane & 15;
    const int rgrp = lane >> 4;
#pragma unroll
    for (int i = 0; i < 8; ++i) {
#pragma unroll
        for (int r = 0; r < 4; ++r) {
            const int gr = bm * BM + waveM * 128 + i * 16 + rgrp * 4 + r;
            const float sc = x_scales[gr];
#pragma unroll
            for (int j = 0; j < 4; ++j) {
                const int gc = bn * BN + waveN * 64 + j * 16 + colT;
                out[(size_t)gr * N_OC + gc] = accF[i][j][r] * sc;
            }
        }
    }
}

// ---------------------------------------------------------------------------
extern "C" void kernel_launch(void* const* d_in, const int* in_sizes, int n_in,
                              void* d_out, int out_size, void* d_ws, size_t ws_size,
                              hipStream_t stream) {
    const float* x          = (const float*)d_in[0];
    const int*   qweight    = (const int*)d_in[1];
    const int*   zeros      = (const int*)d_in[2];
    const int*   qstep      = (const int*)d_in[3];
    const float* base_scale = (const float*)d_in[4];
    const float* step_scale = (const float*)d_in[5];
    float* out = (float*)d_out;

    const int M = in_sizes[0] / K_IC;   // 8192 tokens

    char* ws = (char*)d_ws;
    char*  qx8 = ws;                                         // M*K    = 32 MiB
    char*  w8  = ws + (size_t)M * K_IC;                      // N*K    = 16 MiB
    float* sT  = (float*)(w8 + (size_t)N_OC * K_IC);         // G*N*4  = 512 KiB
    float* xs  = sT + (size_t)GROUPS * N_OC;                 // M*4    = 32 KiB

    prep_kernel<<<M + N_OC, 256, 0, stream>>>(x, qweight, zeros, qstep,
                                              base_scale, step_scale,
                                              qx8, w8, sT, xs, M);

    dim3 grid(N_OC / BN, M / BM);
    gemm_kernel<<<grid, 512, 0, stream>>>(qx8, w8, sT, xs, out);
}

// Round 2
// 450.369 us; speedup vs baseline: 1.0262x; 1.0262x over previous
//
#include <hip/hip_runtime.h>
#include <hip/hip_bf16.h>

typedef int   i32x4 __attribute__((ext_vector_type(4)));
typedef float f32x4 __attribute__((ext_vector_type(4)));

constexpr int K_IC = 4096;   // inner dim
constexpr int N_OC = 4096;   // output channels
constexpr int GROUPS = 32;   // quant groups (group size 128)

// ---------------------------------------------------------------------------
// Fused prep (UNCHANGED this round): blocks [0, M) token quant -> int8;
// blocks [M, M+N_OC) weight prep -> w8 = qw - zero + sT[g][oc] scales.
// ---------------------------------------------------------------------------
__global__ __launch_bounds__(256) void prep_kernel(const float* __restrict__ x,
                                                   const int* __restrict__ qweight,
                                                   const int* __restrict__ zeros,
                                                   const int* __restrict__ qstep,
                                                   const float* __restrict__ base_scales,
                                                   const float* __restrict__ step_scales,
                                                   char* __restrict__ qx8,
                                                   char* __restrict__ w8,
                                                   float* __restrict__ sT,
                                                   float* __restrict__ x_scales,
                                                   int M) {
    const int tid = threadIdx.x;
    if ((int)blockIdx.x < M) {
        // ---- token-wise int8 quant ----
        const int m = blockIdx.x;
        const float4* xr = (const float4*)(x + (size_t)m * K_IC);
        float4 v[4];
        float amax = 0.f;
#pragma unroll
        for (int i = 0; i < 4; ++i) {
            v[i] = xr[i * 256 + tid];
            amax = fmaxf(amax, fmaxf(fmaxf(fabsf(v[i].x), fabsf(v[i].y)),
                                     fmaxf(fabsf(v[i].z), fabsf(v[i].w))));
        }
#pragma unroll
        for (int off = 32; off > 0; off >>= 1)
            amax = fmaxf(amax, __shfl_xor(amax, off, 64));
        __shared__ float wmax[4];
        if ((tid & 63) == 0) wmax[tid >> 6] = amax;
        __syncthreads();
        amax = fmaxf(fmaxf(wmax[0], wmax[1]), fmaxf(wmax[2], wmax[3]));

        const float scale = amax / 127.0f;       // reference x_scales (un-clamped)
        if (tid == 0) x_scales[m] = scale;
        const float inv = 1.0f / fmaxf(scale, 1e-8f);

        char4* qr = (char4*)(qx8 + (size_t)m * K_IC);
#pragma unroll
        for (int i = 0; i < 4; ++i) {
            char4 o;
            o.x = (char)(int)fminf(fmaxf(rintf(v[i].x * inv), -127.f), 127.f);
            o.y = (char)(int)fminf(fmaxf(rintf(v[i].y * inv), -127.f), 127.f);
            o.z = (char)(int)fminf(fmaxf(rintf(v[i].z * inv), -127.f), 127.f);
            o.w = (char)(int)fminf(fmaxf(rintf(v[i].w * inv), -127.f), 127.f);
            qr[i * 256 + tid] = o;
        }
    } else {
        // ---- weight prep: w8 = qw - zero;  sT[g][oc] = base + step*qstep ----
        const int oc = blockIdx.x - M;
        const int4* qwr = (const int4*)(qweight + (size_t)oc * K_IC);
        char4* wr = (char4*)(w8 + (size_t)oc * K_IC);
#pragma unroll
        for (int i = 0; i < 4; ++i) {
            const int idx = i * 256 + tid;          // int4 index within the row
            const int g = idx >> 5;                 // 32 int4 per group of 128
            const int zp = zeros[oc * GROUPS + g];
            int4 a = qwr[idx];
            char4 o;
            o.x = (char)(a.x - zp); o.y = (char)(a.y - zp);
            o.z = (char)(a.z - zp); o.w = (char)(a.w - zp);
            wr[idx] = o;
        }
        if (tid < GROUPS) {
            sT[(size_t)tid * N_OC + oc] =
                base_scales[oc] + step_scales[oc] * (float)qstep[oc * GROUPS + tid];
        }
    }
}

// ---------------------------------------------------------------------------
// int8 MFMA GEMM, 256x256 tile, BK=128 (= group size), 8 waves (2M x 4N),
// per-wave 128x64. Double-buffered LDS, single barrier/tile, prefetch issued
// right after the barrier (loads drain one full tile later -> latency hidden).
// ROUND-2 CHANGE: ILP restructure. Per phase (m-row-pair), all 16 MFMAs are
// emitted as 8 independent chains via explicit p[8] arrays (k0 MFMAs for all
// 8 (i,j) tiles first, then the 8 dependent k1 MFMAs), and the fp32 rescale
// is DEFERRED to after the pure-MFMA cluster. Consumer of each MFMA is >=8
// MFMAs downstream -> result latency covered; setprio(1) wraps the cluster.
// Per group: accF += sT[g][col] * (float)P; P exact (<2^18, no i32 overflow).
// ---------------------------------------------------------------------------
#define BM 256
#define BN 256
#define BK 128

__device__ inline void async16(const char* g, char* l) {
    __builtin_amdgcn_global_load_lds(
        (const __attribute__((address_space(1))) void*)g,
        (__attribute__((address_space(3))) void*)l,
        16, 0, 0);
}

__global__ __launch_bounds__(512, 2) void gemm_kernel(const char* __restrict__ A8,
                                                      const char* __restrict__ B8,
                                                      const float* __restrict__ sT,
                                                      const float* __restrict__ x_scales,
                                                      float* __restrict__ out) {
    __shared__ __attribute__((aligned(16))) char As[2][BM][BK];   // 64 KiB
    __shared__ __attribute__((aligned(16))) char Bs[2][BN][BK];   // 64 KiB

    const int tid  = threadIdx.x;
    const int lane = tid & 63;
    const int wave = tid >> 6;       // 0..7
    const int waveM = wave >> 2;     // 0..1 -> 128 rows each
    const int waveN = wave & 3;      // 0..3 -> 64 cols each

    // T1: XCD-aware swizzle of the flat 512-block grid (nwg % 8 == 0)
    const int GX   = N_OC / BN;                       // 16
    const int flat = blockIdx.y * GX + blockIdx.x;
    const int nwg  = GX * gridDim.y;
    int swz = flat;
    if ((nwg & 7) == 0) swz = (flat & 7) * (nwg >> 3) + (flat >> 3);
    const int bn = swz & (GX - 1);
    const int bm = swz / GX;

    f32x4 accF[8][4] = {};
    const i32x4 zeroq = {0, 0, 0, 0};   // persistent MFMA C-init (D != C)

    // staging: LDS dest = wave-uniform base + lane*16 (linear); the global
    // SOURCE chunk is pre-swizzled: physical chunk p at row r holds logical
    // chunk p ^ (r & 7)  (involution; same XOR applied on the read side)
    const int rowInB = tid >> 3;                                   // 0..63
    const int chunk  = tid & 7;
    const int srcOff = ((chunk ^ (rowInB & 7)) * 16);              // bytes
    const char* Ap = A8 + (size_t)(bm * BM + rowInB) * K_IC + srcOff;
    const char* Bp = B8 + (size_t)(bn * BN + rowInB) * K_IC + srcOff;

    auto STAGE = [&](int b, int t) {
        const int k0 = t * BK;
#pragma unroll
        for (int i = 0; i < 4; ++i)
            async16(Ap + (size_t)(i * 64) * K_IC + k0, &As[b][rowInB + i * 64][chunk * 16]);
#pragma unroll
        for (int i = 0; i < 4; ++i)
            async16(Bp + (size_t)(i * 64) * K_IC + k0, &Bs[b][rowInB + i * 64][chunk * 16]);
    };

    const int mrow = waveM * 128 + (lane & 15);
    const int nrow = waveN * 64 + (lane & 15);
    const int q    = lane >> 4;          // K-quad (16 B each)
    const int sw   = lane & 7;           // row&7 of every fragment row this lane reads
    const int colBase = bn * BN + waveN * 64 + (lane & 15);

    // per-group column scales, software-pipelined one tile ahead
    float scolC[4], scolN[4];
    {
        const float* sg = sT + colBase;
#pragma unroll
        for (int j = 0; j < 4; ++j) scolN[j] = sg[j * 16];
    }

    STAGE(0, 0);

    for (int t = 0; t < GROUPS; ++t) {   // one group == one K-tile (128)
        const int c = t & 1;
        // barrier drain waits on tile t's loads (issued one full tile ago)
        __syncthreads();
        if (t + 1 < GROUPS) STAGE(c ^ 1, t + 1);

#pragma unroll
        for (int j = 0; j < 4; ++j) scolC[j] = scolN[j];
        if (t + 1 < GROUPS) {
            const float* sg = sT + (size_t)(t + 1) * N_OC + colBase;
#pragma unroll
            for (int j = 0; j < 4; ++j) scolN[j] = sg[j * 16];
        }

        // B fragments: held for the whole tile (8 x ds_read_b128, 32 VGPR)
        i32x4 bq[4][2];
#pragma unroll
        for (int j = 0; j < 4; ++j)
#pragma unroll
            for (int kk = 0; kk < 2; ++kk)
                bq[j][kk] = *(const i32x4*)&Bs[c][nrow + j * 16][((kk * 4 + q) ^ sw) * 16];

        // 4 phases over m-pairs; per phase a pure 16-MFMA cluster (8
        // independent chains), then deferred rescale of the 8 p-tiles.
#pragma unroll
        for (int ph = 0; ph < 4; ++ph) {
            const int m0 = mrow + (2 * ph) * 16;
            const int m1 = mrow + (2 * ph + 1) * 16;
            i32x4 a0k0 = *(const i32x4*)&As[c][m0][((0 + q) ^ sw) * 16];
            i32x4 a0k1 = *(const i32x4*)&As[c][m0][((4 + q) ^ sw) * 16];
            i32x4 a1k0 = *(const i32x4*)&As[c][m1][((0 + q) ^ sw) * 16];
            i32x4 a1k1 = *(const i32x4*)&As[c][m1][((4 + q) ^ sw) * 16];

            i32x4 p[8];
            __builtin_amdgcn_s_setprio(1);
#pragma unroll
            for (int j = 0; j < 4; ++j)
                p[j] = __builtin_amdgcn_mfma_i32_16x16x64_i8(a0k0, bq[j][0], zeroq, 0, 0, 0);
#pragma unroll
            for (int j = 0; j < 4; ++j)
                p[4 + j] = __builtin_amdgcn_mfma_i32_16x16x64_i8(a1k0, bq[j][0], zeroq, 0, 0, 0);
#pragma unroll
            for (int j = 0; j < 4; ++j)
                p[j] = __builtin_amdgcn_mfma_i32_16x16x64_i8(a0k1, bq[j][1], p[j], 0, 0, 0);
#pragma unroll
            for (int j = 0; j < 4; ++j)
                p[4 + j] = __builtin_amdgcn_mfma_i32_16x16x64_i8(a1k1, bq[j][1], p[4 + j], 0, 0, 0);
            __builtin_amdgcn_s_setprio(0);

#pragma unroll
            for (int j = 0; j < 4; ++j)
#pragma unroll
                for (int r = 0; r < 4; ++r) {
                    accF[2 * ph][j][r]     += scolC[j] * (float)p[j][r];
                    accF[2 * ph + 1][j][r] += scolC[j] * (float)p[4 + j][r];
                }
        }
    }

    // epilogue: C/D layout col=lane&15, row=(lane>>4)*4+reg (dtype-independent)
    const int colT = lane & 15;
    const int rgrp = lane >> 4;
#pragma unroll
    for (int i = 0; i < 8; ++i) {
#pragma unroll
        for (int r = 0; r < 4; ++r) {
            const int gr = bm * BM + waveM * 128 + i * 16 + rgrp * 4 + r;
            const float sc = x_scales[gr];
#pragma unroll
            for (int j = 0; j < 4; ++j) {
                const int gc = bn * BN + waveN * 64 + j * 16 + colT;
                out[(size_t)gr * N_OC + gc] = accF[i][j][r] * sc;
            }
        }
    }
}

// ---------------------------------------------------------------------------
extern "C" void kernel_launch(void* const* d_in, const int* in_sizes, int n_in,
                              void* d_out, int out_size, void* d_ws, size_t ws_size,
                              hipStream_t stream) {
    const float* x          = (const float*)d_in[0];
    const int*   qweight    = (const int*)d_in[1];
    const int*   zeros      = (const int*)d_in[2];
    const int*   qstep      = (const int*)d_in[3];
    const float* base_scale = (const float*)d_in[4];
    const float* step_scale = (const float*)d_in[5];
    float* out = (float*)d_out;

    const int M = in_sizes[0] / K_IC;   // 8192 tokens

    char* ws = (char*)d_ws;
    char*  qx8 = ws;                                         // M*K    = 32 MiB
    char*  w8  = ws + (size_t)M * K_IC;                      // N*K    = 16 MiB
    float* sT  = (float*)(w8 + (size_t)N_OC * K_IC);         // G*N*4  = 512 KiB
    float* xs  = sT + (size_t)GROUPS * N_OC;                 // M*4    = 32 KiB

    prep_kernel<<<M + N_OC, 256, 0, stream>>>(x, qweight, zeros, qstep,
                                              base_scale, step_scale,
                                              qx8, w8, sT, xs, M);

    dim3 grid(N_OC / BN, M / BM);
    gemm_kernel<<<grid, 512, 0, stream>>>(qx8, w8, sT, xs, out);
}